// Round 10
// baseline (621.269 us; speedup 1.0000x reference)
//
#include <hip/hip_runtime.h>

#define OBS   32
#define NC    512
#define CD    16
#define HD    256
#define BATCH 8192
#define EPS   4e-3f

typedef unsigned short u16;
typedef unsigned int   u32;
typedef __attribute__((ext_vector_type(8))) short bf16x8;   // 8 bf16 = 4 VGPR
typedef __attribute__((ext_vector_type(4))) float f32x4;

__device__ __forceinline__ short f2bf(float x) {            // fp32 -> bf16 RNE
    union { float f; u32 u; } v; v.f = x;
    u32 r = (v.u + 0x7fffu + ((v.u >> 16) & 1u)) >> 16;
    return (short)r;
}
__device__ __forceinline__ float bf2f(short s) {
    union { u32 u; float f; } v; v.u = ((u32)(u16)s) << 16; return v.f;
}

// ---------------------------------------------------------------------------
// Kernel 0 (prep): norms + fcnt; W1 split hi/lo in B-frag chunk order;
// W2t split (stride 264); codebook B-frags (hi/lo per 16-code tile) with the
// K-packed layout: frag[l][j] = c_{hi|lo}[n = t*16 + (l&15)][((l>>4)&1)*8+j].
// ---------------------------------------------------------------------------
__global__ void prep_kernel(const float* __restrict__ cb,
                            const float* __restrict__ W1,
                            const float* __restrict__ W2,
                            float* __restrict__ n32, double* __restrict__ n64,
                            int* __restrict__ fcnt,
                            u16* __restrict__ wsW1, u16* __restrict__ wsW2,
                            u16* __restrict__ wsCB) {
    const int b = blockIdx.x, t = threadIdx.x;
    if (b == 0) {
        if (t == 0) *fcnt = 0;
        #pragma unroll
        for (int h = 0; h < 2; ++h) {
            int c = t + h * 256;
            const float* r = cb + c * CD;
            float s32 = 0.f; double s64 = 0.0;
            #pragma unroll
            for (int j = 0; j < CD; ++j) {
                float v = r[j];
                s32 = fmaf(v, v, s32);
                s64 = fma((double)v, (double)v, s64);
            }
            n32[c] = s32; n64[c] = s64;
        }
    } else if (b <= 256) {
        int e = (b - 1) * 256 + t;          // e = k*256 + n
        int k = e >> 8, n = e & 255;
        float w = W1[k * 256 + n];
        short hi = f2bf(w);
        short lo = f2bf(w - bf2f(hi));
        int s = k >> 5, koff = k & 31;
        wsW1[s * 16384 + n * 32 + koff]        = (u16)hi;
        wsW1[s * 16384 + 8192 + n * 32 + koff] = (u16)lo;
    } else if (b == 257) {                   // W2 (4096 elems)
        #pragma unroll
        for (int i = 0; i < 16; ++i) {
            int e = t * 16 + i;              // e = k*16 + n
            int k = e >> 4, n = e & 15;
            float w = W2[k * CD + n];
            short hi = f2bf(w);
            short lo = f2bf(w - bf2f(hi));
            wsW2[n * 264 + k]        = (u16)hi;
            wsW2[4224 + n * 264 + k] = (u16)lo;
        }
    } else {                                 // b == 258: codebook B-frags
        #pragma unroll
        for (int i = 0; i < 8; ++i) {
            int sl = t * 8 + i;              // (tile, lane) slot, 2048 total
            int tile = sl >> 6, l = sl & 63;
            int n  = tile * 16 + (l & 15);
            int kb = ((l >> 4) & 1) * 8;
            u16* dh = wsCB + tile * 1024 + l * 8;
            u16* dl = dh + 512;
            #pragma unroll
            for (int j = 0; j < 8; ++j) {
                float w = cb[n * CD + kb + j];
                short hi = f2bf(w);
                dh[j] = (u16)hi;
                dl[j] = (u16)f2bf(w - bf2f(hi));
            }
        }
    }
}

// ---------------------------------------------------------------------------
// Kernel 1: MFMA encoder. One block = one batch row (32 tokens), 256 thr.
// Wave w: M-tile mt=w&1, N-half ng=w>>1. Phases A/B/C as R9 (verified).
// Phase D: distances via K-packed split MFMA (A=[e_hi|e_lo], B=[c_hi|c_hi]
// then [c_lo|c_lo]); top-2 selection on C-frags; width-16 shuffle reduce;
// cross-N-half merge via LDS; gap < EPS -> fp64 fixup.
// ---------------------------------------------------------------------------
__global__ void __launch_bounds__(256) encoder_kernel(
    const float* __restrict__ obs,
    const float* __restrict__ W0, const float* __restrict__ B0,
    const float* __restrict__ B1, const float* __restrict__ B2,
    const u16* __restrict__ wsW1, const u16* __restrict__ wsW2,
    const u16* __restrict__ wsCB, const float* __restrict__ n32,
    int* __restrict__ idxbuf, int* __restrict__ fcnt, int* __restrict__ flist)
{
    __shared__ u32   hpk[32 * 260];  // 33280 B: h1 packed (hi<<16|lo)
    __shared__ float embs[OBS * CD]; //  2048 B
    __shared__ float redD[2][OBS][2];//   512 B
    __shared__ int   redI[2][OBS][2];//   512 B

    const int tid = threadIdx.x;
    const int blk = blockIdx.x;
    const int l   = tid & 63;
    const int wv  = tid >> 6;
    const int q   = l >> 4;          // quad 0..3
    const int ln  = l & 15;
    const int mt  = wv & 1;
    const int ng  = wv >> 1;

    // ---- phase A: h0 A-frags in registers (lane: m = mt*16+ln) ----
    bf16x8 Ah[8], Al[8];
    {
        const int m = mt * 16 + ln;
        const float x = obs[blk * OBS + m];
        const float* W0r = W0 + (1 + m) * HD;
        #pragma unroll
        for (int s = 0; s < 8; ++s) {
            const int k0 = s * 32 + q * 8;
            float w0v[8], wmv[8], b0v[8];
            *(float4*)&w0v[0] = *(const float4*)(W0 + k0);
            *(float4*)&w0v[4] = *(const float4*)(W0 + k0 + 4);
            *(float4*)&wmv[0] = *(const float4*)(W0r + k0);
            *(float4*)&wmv[4] = *(const float4*)(W0r + k0 + 4);
            *(float4*)&b0v[0] = *(const float4*)(B0 + k0);
            *(float4*)&b0v[4] = *(const float4*)(B0 + k0 + 4);
            #pragma unroll
            for (int j = 0; j < 8; ++j) {
                float h = fmaxf(fmaf(x, w0v[j], wmv[j]) + b0v[j], 0.f);
                short hi = f2bf(h);
                short lo = f2bf(h - bf2f(hi));
                Ah[s][j] = hi; Al[s][j] = lo;
            }
        }
    }

    // ---- phase B: h1 = relu(h0 @ W1 + b1) via 3-pass split MFMA ----
    f32x4 acc[8];
    #pragma unroll
    for (int nt = 0; nt < 8; ++nt) acc[nt] = (f32x4){0.f, 0.f, 0.f, 0.f};
    {
        const u16* pB = wsW1 + (ng * 128 + ln) * 32 + q * 8;
        #pragma unroll
        for (int s = 0; s < 8; ++s) {
            const u16* ph = pB + s * 16384;
            const u16* pl = ph + 8192;
            #pragma unroll
            for (int nt = 0; nt < 8; ++nt) {
                bf16x8 Bh = *(const bf16x8*)(ph + nt * 512);
                bf16x8 Bl = *(const bf16x8*)(pl + nt * 512);
                f32x4 a = acc[nt];
                a = __builtin_amdgcn_mfma_f32_16x16x32_bf16(Ah[s], Bh, a, 0, 0, 0);
                a = __builtin_amdgcn_mfma_f32_16x16x32_bf16(Ah[s], Bl, a, 0, 0, 0);
                a = __builtin_amdgcn_mfma_f32_16x16x32_bf16(Al[s], Bh, a, 0, 0, 0);
                acc[nt] = a;
            }
        }
    }

    {   // h1 epilogue: relu(+b1), split, pack -> hpk[m][n] (stride 260)
        #pragma unroll
        for (int nt = 0; nt < 8; ++nt) {
            const int n = ng * 128 + nt * 16 + ln;
            const float b1 = B1[n];
            #pragma unroll
            for (int r = 0; r < 4; ++r) {
                float h = fmaxf(acc[nt][r] + b1, 0.f);
                short hi = f2bf(h);
                short lo = f2bf(h - bf2f(hi));
                const int mr = mt * 16 + q * 4 + r;
                hpk[mr * 260 + n] = ((u32)(u16)hi << 16) | (u32)(u16)lo;
            }
        }
    }
    __syncthreads();

    // ---- phase C: emb = h1 @ W2 + b2 (waves 0,1; M-tile = wv) ----
    if (wv < 2) {
        f32x4 ac = (f32x4){0.f, 0.f, 0.f, 0.f};
        const u32* pA  = hpk + (wv * 16 + ln) * 260;
        const u16* pWh = wsW2 + ln * 264 + q * 8;
        const u16* pWl = pWh + 4224;
        #pragma unroll
        for (int s = 0; s < 8; ++s) {
            uint4 pa = *(const uint4*)(pA + s * 32 + q * 8);
            uint4 pb = *(const uint4*)(pA + s * 32 + q * 8 + 4);
            bf16x8 Ah2 = { (short)(pa.x >> 16), (short)(pa.y >> 16),
                           (short)(pa.z >> 16), (short)(pa.w >> 16),
                           (short)(pb.x >> 16), (short)(pb.y >> 16),
                           (short)(pb.z >> 16), (short)(pb.w >> 16) };
            bf16x8 Al2 = { (short)pa.x, (short)pa.y, (short)pa.z, (short)pa.w,
                           (short)pb.x, (short)pb.y, (short)pb.z, (short)pb.w };
            bf16x8 Bh = *(const bf16x8*)(pWh + s * 32);
            bf16x8 Bl = *(const bf16x8*)(pWl + s * 32);
            ac = __builtin_amdgcn_mfma_f32_16x16x32_bf16(Ah2, Bh, ac, 0, 0, 0);
            ac = __builtin_amdgcn_mfma_f32_16x16x32_bf16(Ah2, Bl, ac, 0, 0, 0);
            ac = __builtin_amdgcn_mfma_f32_16x16x32_bf16(Al2, Bh, ac, 0, 0, 0);
        }
        const float b2 = B2[ln];
        #pragma unroll
        for (int r = 0; r < 4; ++r)
            embs[(wv * 16 + q * 4 + r) * CD + ln] = ac[r] + b2;
    }
    __syncthreads();                 // embs ready

    // ---- phase D: distances via K-packed split MFMA + top-2 ----
    {
        // A-frag: q<2 -> e_hi[k0..15], q>=2 -> e_lo[k0..15], token m=mt*16+ln
        bf16x8 Ae;
        {
            const float* ep = embs + (mt * 16 + ln) * CD + (q & 1) * 8;
            float4 ea = *(const float4*)ep;
            float4 eb = *(const float4*)(ep + 4);
            float ev[8] = { ea.x, ea.y, ea.z, ea.w, eb.x, eb.y, eb.z, eb.w };
            #pragma unroll
            for (int j = 0; j < 8; ++j) {
                short hi = f2bf(ev[j]);
                Ae[j] = (q < 2) ? hi : f2bf(ev[j] - bf2f(hi));
            }
        }
        float d1[4], d2[4]; int i1[4], i2[4];
        #pragma unroll
        for (int r = 0; r < 4; ++r) { d1[r] = d2[r] = 3.4e38f; i1[r] = i2[r] = 0x7fffffff; }

        const u16* pC = wsCB + (ng * 16) * 1024 + l * 8;
        #pragma unroll
        for (int tb = 0; tb < 16; tb += 4) {
            f32x4 ac4[4];
            #pragma unroll
            for (int u = 0; u < 4; ++u) {
                const u16* pt = pC + (tb + u) * 1024;
                bf16x8 Bh = *(const bf16x8*)pt;
                bf16x8 Bl = *(const bf16x8*)(pt + 512);
                f32x4 a = (f32x4){0.f, 0.f, 0.f, 0.f};
                a = __builtin_amdgcn_mfma_f32_16x16x32_bf16(Ae, Bh, a, 0, 0, 0);
                a = __builtin_amdgcn_mfma_f32_16x16x32_bf16(Ae, Bl, a, 0, 0, 0);
                ac4[u] = a;
            }
            #pragma unroll
            for (int u = 0; u < 4; ++u) {
                const int ci = (ng * 16 + tb + u) * 16 + ln;
                const float cn = n32[ci];
                #pragma unroll
                for (int r = 0; r < 4; ++r) {
                    float d = fmaf(-2.f, ac4[u][r], cn);
                    if (d < d1[r])      { d2[r] = d1[r]; i2[r] = i1[r]; d1[r] = d; i1[r] = ci; }
                    else if (d < d2[r]) { d2[r] = d;  i2[r] = ci; }
                }
            }
        }
        // reduce over the 16 lanes of the quad (tie -> low index)
        #pragma unroll
        for (int off = 8; off >= 1; off >>= 1) {
            #pragma unroll
            for (int r = 0; r < 4; ++r) {
                float od1 = __shfl_down(d1[r], off, 16);
                int   oi1 = __shfl_down(i1[r], off, 16);
                float od2 = __shfl_down(d2[r], off, 16);
                int   oi2 = __shfl_down(i2[r], off, 16);
                bool ob = (od1 < d1[r]) || (od1 == d1[r] && oi1 < i1[r]);
                float n1d, n2d; int n1i, n2i;
                if (ob) {
                    n1d = od1; n1i = oi1;
                    bool t2 = (d1[r] < od2) || (d1[r] == od2 && i1[r] < oi2);
                    n2d = t2 ? d1[r] : od2; n2i = t2 ? i1[r] : oi2;
                } else {
                    n1d = d1[r]; n1i = i1[r];
                    bool t2 = (od1 < d2[r]) || (od1 == d2[r] && oi1 < i2[r]);
                    n2d = t2 ? od1 : d2[r]; n2i = t2 ? oi1 : i2[r];
                }
                d1[r] = n1d; i1[r] = n1i; d2[r] = n2d; i2[r] = n2i;
            }
        }
        if (ln == 0) {
            #pragma unroll
            for (int r = 0; r < 4; ++r) {
                const int m = mt * 16 + q * 4 + r;
                redD[ng][m][0] = d1[r]; redD[ng][m][1] = d2[r];
                redI[ng][m][0] = i1[r]; redI[ng][m][1] = i2[r];
            }
        }
    }
    __syncthreads();

    if (tid < OBS) {                 // merge the two N-halves, flag, write idx
        const int m = tid;
        float d1 = redD[0][m][0], d2 = redD[0][m][1];
        int   i1 = redI[0][m][0], i2 = redI[0][m][1];
        #pragma unroll
        for (int h = 0; h < 2; ++h) {
            float db = redD[1][m][h]; int ib = redI[1][m][h];
            if (db < d1 || (db == d1 && ib < i1)) { d2 = d1; i2 = i1; d1 = db; i1 = ib; }
            else if (db < d2 || (db == d2 && ib < i2)) { d2 = db; i2 = ib; }
        }
        const int T = blk * OBS + m;
        idxbuf[T] = i1;
        if (d2 - d1 < EPS) {
            int pos = atomicAdd(fcnt, 1);
            flist[pos] = T;
        }
    }
}

// ---------------------------------------------------------------------------
// Kernel 2: fp64 exact re-solve for flagged tokens (from ORIGINAL fp32 data).
// ---------------------------------------------------------------------------
__global__ void __launch_bounds__(256) fixup_kernel(
    const float* __restrict__ obs,
    const float* __restrict__ W0, const float* __restrict__ B0,
    const float* __restrict__ W1, const float* __restrict__ B1,
    const float* __restrict__ W2, const float* __restrict__ B2,
    const float* __restrict__ cb, const double* __restrict__ n64,
    const int* __restrict__ fcnt, const int* __restrict__ flist,
    int* __restrict__ idxbuf)
{
    __shared__ double h0s[HD];
    __shared__ double h1s[HD];
    __shared__ double ep[16][17];
    __shared__ double es[CD];
    __shared__ double dmin[256];
    __shared__ int    imin[256];

    int n = *fcnt;
    if (n > BATCH * OBS) n = BATCH * OBS;
    const int j = threadIdx.x;

    for (int f = blockIdx.x; f < n; f += gridDim.x) {
        const int T = flist[f];
        const int b = T >> 5, t = T & 31;
        const double x = (double)obs[b * OBS + t];
        {
            double a = fma(x, (double)W0[j], (double)W0[(1 + t) * HD + j])
                     + (double)B0[j];
            h0s[j] = a > 0.0 ? a : 0.0;
        }
        __syncthreads();
        {
            double s = 0.0;
            for (int k = 0; k < HD; ++k)
                s = fma(h0s[k], (double)W1[k * HD + j], s);
            s += (double)B1[j];
            h1s[j] = s > 0.0 ? s : 0.0;
        }
        __syncthreads();
        {
            const int d = j & 15, part = j >> 4;
            double s = 0.0;
            for (int k = part * 16; k < part * 16 + 16; ++k)
                s = fma(h1s[k], (double)W2[k * CD + d], s);
            ep[part][d] = s;
        }
        __syncthreads();
        if (j < CD) {
            double s = 0.0;
            for (int p = 0; p < 16; ++p) s += ep[p][j];
            es[j] = s + (double)B2[j];
        }
        __syncthreads();
        {
            double best = 1e300; int bi = 0x7fffffff;
            for (int c = j; c < NC; c += 256) {
                double dot = 0.0;
                #pragma unroll
                for (int qq = 0; qq < CD; ++qq)
                    dot = fma(es[qq], (double)cb[c * CD + qq], dot);
                double D = n64[c] - 2.0 * dot;
                if (D < best || (D == best && c < bi)) { best = D; bi = c; }
            }
            dmin[j] = best; imin[j] = bi;
        }
        __syncthreads();
        if (j == 0) {
            double best = dmin[0]; int bi = imin[0];
            for (int k = 1; k < 256; ++k)
                if (dmin[k] < best || (dmin[k] == best && imin[k] < bi)) {
                    best = dmin[k]; bi = imin[k];
                }
            idxbuf[T] = bi;
        }
        __syncthreads();
    }
}

// ---------------------------------------------------------------------------
// Kernel 3: decoder MLP 512 -> 256 -> 256 -> 32, 16 batch rows per block.
// ---------------------------------------------------------------------------
__global__ void __launch_bounds__(256) decoder_kernel(
    const int* __restrict__ idx, const float* __restrict__ cbk,
    const float* __restrict__ W0, const float* __restrict__ B0,
    const float* __restrict__ W1, const float* __restrict__ B1,
    const float* __restrict__ W2, const float* __restrict__ B2,
    float* __restrict__ out)
{
    __shared__ float qb[16][512];
    __shared__ float hb[16][256];
    const int tid = threadIdx.x;
    const int row0 = blockIdx.x * 16;

    {
        const int base = row0 * OBS;
        #pragma unroll
        for (int m = 0; m < 2; ++m) {
            int g = tid * 2 + m;
            int ciq = idx[base + g];
            const float4* src = (const float4*)(cbk + ciq * CD);
            float4* dst = (float4*)&qb[g >> 5][(g & 31) * CD];
            dst[0] = src[0]; dst[1] = src[1]; dst[2] = src[2]; dst[3] = src[3];
        }
    }
    __syncthreads();

    const int jg = tid & 63, tg = tid >> 6;
    const int j0 = jg * 4, r0 = tg * 4;

    {
        float acA[4][4], acB[4][4];
        #pragma unroll
        for (int tt = 0; tt < 4; ++tt)
            #pragma unroll
            for (int u = 0; u < 4; ++u) { acA[tt][u] = 0.f; acB[tt][u] = 0.f; }
        for (int k = 0; k < 512; k += 4) {
            float hr[4][4];
            #pragma unroll
            for (int tt = 0; tt < 4; ++tt) {
                float4 hv = *(const float4*)&qb[r0 + tt][k];
                hr[tt][0] = hv.x; hr[tt][1] = hv.y; hr[tt][2] = hv.z; hr[tt][3] = hv.w;
            }
            #pragma unroll
            for (int p = 0; p < 4; ++p) {
                float4 w = *(const float4*)(W0 + (k + p) * 256 + j0);
                if (p < 2) {
                    #pragma unroll
                    for (int tt = 0; tt < 4; ++tt) {
                        acA[tt][0] = fmaf(hr[tt][p], w.x, acA[tt][0]);
                        acA[tt][1] = fmaf(hr[tt][p], w.y, acA[tt][1]);
                        acA[tt][2] = fmaf(hr[tt][p], w.z, acA[tt][2]);
                        acA[tt][3] = fmaf(hr[tt][p], w.w, acA[tt][3]);
                    }
                } else {
                    #pragma unroll
                    for (int tt = 0; tt < 4; ++tt) {
                        acB[tt][0] = fmaf(hr[tt][p], w.x, acB[tt][0]);
                        acB[tt][1] = fmaf(hr[tt][p], w.y, acB[tt][1]);
                        acB[tt][2] = fmaf(hr[tt][p], w.z, acB[tt][2]);
                        acB[tt][3] = fmaf(hr[tt][p], w.w, acB[tt][3]);
                    }
                }
            }
        }
        #pragma unroll
        for (int tt = 0; tt < 4; ++tt)
            #pragma unroll
            for (int u = 0; u < 4; ++u)
                hb[r0 + tt][j0 + u] = fmaxf((acA[tt][u] + acB[tt][u]) + B0[j0 + u], 0.f);
    }
    __syncthreads();

    float* h2 = &qb[0][0];
    {
        float acA[4][4], acB[4][4];
        #pragma unroll
        for (int tt = 0; tt < 4; ++tt)
            #pragma unroll
            for (int u = 0; u < 4; ++u) { acA[tt][u] = 0.f; acB[tt][u] = 0.f; }
        for (int k = 0; k < 256; k += 4) {
            float hr[4][4];
            #pragma unroll
            for (int tt = 0; tt < 4; ++tt) {
                float4 hv = *(const float4*)&hb[r0 + tt][k];
                hr[tt][0] = hv.x; hr[tt][1] = hv.y; hr[tt][2] = hv.z; hr[tt][3] = hv.w;
            }
            #pragma unroll
            for (int p = 0; p < 4; ++p) {
                float4 w = *(const float4*)(W1 + (k + p) * 256 + j0);
                if (p < 2) {
                    #pragma unroll
                    for (int tt = 0; tt < 4; ++tt) {
                        acA[tt][0] = fmaf(hr[tt][p], w.x, acA[tt][0]);
                        acA[tt][1] = fmaf(hr[tt][p], w.y, acA[tt][1]);
                        acA[tt][2] = fmaf(hr[tt][p], w.z, acA[tt][2]);
                        acA[tt][3] = fmaf(hr[tt][p], w.w, acA[tt][3]);
                    }
                } else {
                    #pragma unroll
                    for (int tt = 0; tt < 4; ++tt) {
                        acB[tt][0] = fmaf(hr[tt][p], w.x, acB[tt][0]);
                        acB[tt][1] = fmaf(hr[tt][p], w.y, acB[tt][1]);
                        acB[tt][2] = fmaf(hr[tt][p], w.z, acB[tt][2]);
                        acB[tt][3] = fmaf(hr[tt][p], w.w, acB[tt][3]);
                    }
                }
            }
        }
        __syncthreads();
        #pragma unroll
        for (int tt = 0; tt < 4; ++tt)
            #pragma unroll
            for (int u = 0; u < 4; ++u)
                h2[(r0 + tt) * 256 + j0 + u] =
                    fmaxf((acA[tt][u] + acB[tt][u]) + B1[j0 + u], 0.f);
    }
    __syncthreads();

    {
        const int c  = tid & 31;
        const int rg = tid >> 5;
        for (int rr = rg; rr < 16; rr += 8) {
            float a0 = 0.f, a1 = 0.f, a2 = 0.f, a3 = 0.f;
            #pragma unroll 4
            for (int k = 0; k < 256; k += 4) {
                float4 hv = *(const float4*)&h2[rr * 256 + k];
                a0 = fmaf(hv.x, W2[(k + 0) * 32 + c], a0);
                a1 = fmaf(hv.y, W2[(k + 1) * 32 + c], a1);
                a2 = fmaf(hv.z, W2[(k + 2) * 32 + c], a2);
                a3 = fmaf(hv.w, W2[(k + 3) * 32 + c], a3);
            }
            out[(row0 + rr) * 32 + c] = ((a0 + a1) + (a2 + a3)) + B2[c];
        }
    }
}

// ---------------------------------------------------------------------------
extern "C" void kernel_launch(void* const* d_in, const int* in_sizes, int n_in,
                              void* d_out, int out_size, void* d_ws, size_t ws_size,
                              hipStream_t stream) {
    (void)in_sizes; (void)n_in; (void)out_size; (void)ws_size;
    const float* obs = (const float*)d_in[0];
    const float* eW0 = (const float*)d_in[1];
    const float* eb0 = (const float*)d_in[2];
    const float* eW1 = (const float*)d_in[3];
    const float* eb1 = (const float*)d_in[4];
    const float* eW2 = (const float*)d_in[5];
    const float* eb2 = (const float*)d_in[6];
    const float* dW0 = (const float*)d_in[7];
    const float* db0 = (const float*)d_in[8];
    const float* dW1 = (const float*)d_in[9];
    const float* db1 = (const float*)d_in[10];
    const float* dW2 = (const float*)d_in[11];
    const float* db2 = (const float*)d_in[12];
    const float* cb  = (const float*)d_in[13];

    char*   ws    = (char*)d_ws;
    float*  n32   = (float*)ws;                          // 2 KB
    double* n64   = (double*)(ws + 4096);                // 4 KB
    int*    fcnt  = (int*)(ws + 8192);                   // 4 B
    int*    flist = (int*)(ws + 8448);                   // 1 MB
    int*    idxb  = (int*)(ws + 8448 + 1048576);         // 1 MB
    u16*    wsW1  = (u16*)(ws + 4194304);                // 256 KB
    u16*    wsW2  = (u16*)(ws + 4194304 + 262144);       // 16.5 KB (pad 32 KB)
    u16*    wsCB  = (u16*)(ws + 4194304 + 262144 + 32768); // 64 KB

    prep_kernel<<<259, 256, 0, stream>>>(cb, eW1, eW2, n32, n64, fcnt,
                                         wsW1, wsW2, wsCB);
    encoder_kernel<<<BATCH, 256, 0, stream>>>(obs, eW0, eb0, eb1, eb2,
                                              wsW1, wsW2, wsCB, n32,
                                              idxb, fcnt, flist);
    fixup_kernel<<<256, 256, 0, stream>>>(obs, eW0, eb0, eW1, eb1, eW2, eb2,
                                          cb, n64, fcnt, flist, idxb);
    decoder_kernel<<<BATCH / 16, 256, 0, stream>>>(idxb, cb, dW0, db0, dW1, db1,
                                                   dW2, db2, (float*)d_out);
}

// Round 11
// 456.953 us; speedup vs baseline: 1.3596x; 1.3596x over previous
//
#include <hip/hip_runtime.h>

#define OBS   32
#define NC    512
#define CD    16
#define HD    256
#define BATCH 8192
#define EPS   4e-3f

typedef unsigned short u16;
typedef unsigned int   u32;
typedef __attribute__((ext_vector_type(8))) short bf16x8;   // 8 bf16 = 4 VGPR
typedef __attribute__((ext_vector_type(4))) float f32x4;

__device__ __forceinline__ short f2bf(float x) {            // fp32 -> bf16 RNE
    union { float f; u32 u; } v; v.f = x;
    u32 r = (v.u + 0x7fffu + ((v.u >> 16) & 1u)) >> 16;
    return (short)r;
}
__device__ __forceinline__ float bf2f(short s) {
    union { u32 u; float f; } v; v.u = ((u32)(u16)s) << 16; return v.f;
}

// ---------------------------------------------------------------------------
// Kernel 0 (prep): norms + fcnt; W1 split hi/lo in B-frag chunk order;
// W2t split (stride 264); codebook B-frags (hi/lo per 16-code tile, K-packed
// duplication: frag[l][j] = c[n = t*16 + (l&15)][((l>>4)&1)*8+j]).
// ---------------------------------------------------------------------------
__global__ void prep_kernel(const float* __restrict__ cb,
                            const float* __restrict__ W1,
                            const float* __restrict__ W2,
                            float* __restrict__ n32, double* __restrict__ n64,
                            int* __restrict__ fcnt,
                            u16* __restrict__ wsW1, u16* __restrict__ wsW2,
                            u16* __restrict__ wsCB) {
    const int b = blockIdx.x, t = threadIdx.x;
    if (b == 0) {
        if (t == 0) *fcnt = 0;
        #pragma unroll
        for (int h = 0; h < 2; ++h) {
            int c = t + h * 256;
            const float* r = cb + c * CD;
            float s32 = 0.f; double s64 = 0.0;
            #pragma unroll
            for (int j = 0; j < CD; ++j) {
                float v = r[j];
                s32 = fmaf(v, v, s32);
                s64 = fma((double)v, (double)v, s64);
            }
            n32[c] = s32; n64[c] = s64;
        }
    } else if (b <= 256) {
        int e = (b - 1) * 256 + t;          // e = k*256 + n
        int k = e >> 8, n = e & 255;
        float w = W1[k * 256 + n];
        short hi = f2bf(w);
        short lo = f2bf(w - bf2f(hi));
        int s = k >> 5, koff = k & 31;
        wsW1[s * 16384 + n * 32 + koff]        = (u16)hi;
        wsW1[s * 16384 + 8192 + n * 32 + koff] = (u16)lo;
    } else if (b == 257) {                   // W2 (4096 elems)
        #pragma unroll
        for (int i = 0; i < 16; ++i) {
            int e = t * 16 + i;              // e = k*16 + n
            int k = e >> 4, n = e & 15;
            float w = W2[k * CD + n];
            short hi = f2bf(w);
            short lo = f2bf(w - bf2f(hi));
            wsW2[n * 264 + k]        = (u16)hi;
            wsW2[4224 + n * 264 + k] = (u16)lo;
        }
    } else {                                 // b == 258: codebook B-frags
        #pragma unroll
        for (int i = 0; i < 8; ++i) {
            int sl = t * 8 + i;              // (tile, lane) slot, 2048 total
            int tile = sl >> 6, l = sl & 63;
            int n  = tile * 16 + (l & 15);
            int kb = ((l >> 4) & 1) * 8;
            u16* dh = wsCB + tile * 1024 + l * 8;
            u16* dl = dh + 512;
            #pragma unroll
            for (int j = 0; j < 8; ++j) {
                float w = cb[n * CD + kb + j];
                short hi = f2bf(w);
                dh[j] = (u16)hi;
                dl[j] = (u16)f2bf(w - bf2f(hi));
            }
        }
    }
}

// ---------------------------------------------------------------------------
// Kernel 1: MFMA encoder. One block = one batch row (32 tokens), 256 thr.
// Wave wv owns BOTH M-tiles x N-quarter nq=wv (4 N-tiles): each B-frag load
// feeds 6 MFMAs (3-term split x 2 M-tiles) -> half the global loads of R10.
// Phase A computed ONCE (waves 0,1), packed hi|lo into LDS; all waves unpack
// A-frags from LDS. Phase D: wave = code quarter, 2 token-sets via K-packed
// split MFMA. Top-2 + EPS flag -> fp64 fixup.
// ---------------------------------------------------------------------------
__global__ void __launch_bounds__(256) encoder_kernel(
    const float* __restrict__ obs,
    const float* __restrict__ W0, const float* __restrict__ B0,
    const float* __restrict__ B1, const float* __restrict__ B2,
    const u16* __restrict__ wsW1, const u16* __restrict__ wsW2,
    const u16* __restrict__ wsCB, const float* __restrict__ n32,
    int* __restrict__ idxbuf, int* __restrict__ fcnt, int* __restrict__ flist)
{
    __shared__ u32   hpk[32 * 260];  // 33280 B: h0 packed, then h1 packed
    __shared__ float embs[OBS * CD]; //  2048 B
    __shared__ float redD[4][OBS][2];//  1024 B
    __shared__ int   redI[4][OBS][2];//  1024 B   (37376 B -> 4 blk/CU)

    const int tid = threadIdx.x;
    const int blk = blockIdx.x;
    const int l   = tid & 63;
    const int wv  = tid >> 6;
    const int q   = l >> 4;          // quad 0..3
    const int ln  = l & 15;
    const int nq  = wv;              // N-quarter (cols nq*64 .. +63)

    // ---- phase A (waves 0,1): h0 tokens wv*16+ln, pack hi|lo -> hpk ----
    if (wv < 2) {
        const int m = wv * 16 + ln;
        const float x = obs[blk * OBS + m];
        const float* W0r = W0 + (1 + m) * HD;
        #pragma unroll
        for (int s = 0; s < 8; ++s) {
            const int k0 = s * 32 + q * 8;
            float w0v[8], wmv[8], b0v[8];
            *(float4*)&w0v[0] = *(const float4*)(W0 + k0);
            *(float4*)&w0v[4] = *(const float4*)(W0 + k0 + 4);
            *(float4*)&wmv[0] = *(const float4*)(W0r + k0);
            *(float4*)&wmv[4] = *(const float4*)(W0r + k0 + 4);
            *(float4*)&b0v[0] = *(const float4*)(B0 + k0);
            *(float4*)&b0v[4] = *(const float4*)(B0 + k0 + 4);
            u32 pk[8];
            #pragma unroll
            for (int j = 0; j < 8; ++j) {
                float h = fmaxf(fmaf(x, w0v[j], wmv[j]) + b0v[j], 0.f);
                short hi = f2bf(h);
                short lo = f2bf(h - bf2f(hi));
                pk[j] = ((u32)(u16)hi << 16) | (u32)(u16)lo;
            }
            *(uint4*)&hpk[m * 260 + k0]     = *(uint4*)&pk[0];
            *(uint4*)&hpk[m * 260 + k0 + 4] = *(uint4*)&pk[4];
        }
    }
    __syncthreads();

    // ---- phase B: h1 = relu(h0 @ W1 + b1); both M-tiles, 4 N-tiles ----
    f32x4 acc[2][4];
    #pragma unroll
    for (int mt = 0; mt < 2; ++mt)
        #pragma unroll
        for (int nt = 0; nt < 4; ++nt) acc[mt][nt] = (f32x4){0.f, 0.f, 0.f, 0.f};

    {
        const u16* pB = wsW1 + (nq * 64 + ln) * 32 + q * 8;
        #pragma unroll
        for (int s = 0; s < 8; ++s) {
            bf16x8 AH[2], AL[2];
            #pragma unroll
            for (int mt = 0; mt < 2; ++mt) {
                const u32* pa4 = &hpk[(mt * 16 + ln) * 260 + s * 32 + q * 8];
                uint4 pa = *(const uint4*)pa4;
                uint4 pb = *(const uint4*)(pa4 + 4);
                AH[mt] = (bf16x8){ (short)(pa.x >> 16), (short)(pa.y >> 16),
                                   (short)(pa.z >> 16), (short)(pa.w >> 16),
                                   (short)(pb.x >> 16), (short)(pb.y >> 16),
                                   (short)(pb.z >> 16), (short)(pb.w >> 16) };
                AL[mt] = (bf16x8){ (short)pa.x, (short)pa.y,
                                   (short)pa.z, (short)pa.w,
                                   (short)pb.x, (short)pb.y,
                                   (short)pb.z, (short)pb.w };
            }
            const u16* ph = pB + s * 16384;
            const u16* pl = ph + 8192;
            #pragma unroll
            for (int nt = 0; nt < 4; ++nt) {
                bf16x8 Bh = *(const bf16x8*)(ph + nt * 512);
                bf16x8 Bl = *(const bf16x8*)(pl + nt * 512);
                #pragma unroll
                for (int mt = 0; mt < 2; ++mt) {
                    f32x4 a = acc[mt][nt];
                    a = __builtin_amdgcn_mfma_f32_16x16x32_bf16(AH[mt], Bh, a, 0, 0, 0);
                    a = __builtin_amdgcn_mfma_f32_16x16x32_bf16(AH[mt], Bl, a, 0, 0, 0);
                    a = __builtin_amdgcn_mfma_f32_16x16x32_bf16(AL[mt], Bh, a, 0, 0, 0);
                    acc[mt][nt] = a;
                }
            }
        }
    }
    __syncthreads();                 // all h0 reads done before h1 overlay

    {   // h1 epilogue: relu(+b1), split, pack -> hpk[m][n] (stride 260)
        #pragma unroll
        for (int nt = 0; nt < 4; ++nt) {
            const int n = nq * 64 + nt * 16 + ln;
            const float b1 = B1[n];
            #pragma unroll
            for (int mt = 0; mt < 2; ++mt) {
                #pragma unroll
                for (int r = 0; r < 4; ++r) {
                    float h = fmaxf(acc[mt][nt][r] + b1, 0.f);
                    short hi = f2bf(h);
                    short lo = f2bf(h - bf2f(hi));
                    const int mr = mt * 16 + q * 4 + r;
                    hpk[mr * 260 + n] = ((u32)(u16)hi << 16) | (u32)(u16)lo;
                }
            }
        }
    }
    __syncthreads();

    // ---- phase C: emb = h1 @ W2 + b2 (waves 0,1; M-tile = wv) ----
    if (wv < 2) {
        f32x4 ac = (f32x4){0.f, 0.f, 0.f, 0.f};
        const u32* pA  = hpk + (wv * 16 + ln) * 260;
        const u16* pWh = wsW2 + ln * 264 + q * 8;
        const u16* pWl = pWh + 4224;
        #pragma unroll
        for (int s = 0; s < 8; ++s) {
            uint4 pa = *(const uint4*)(pA + s * 32 + q * 8);
            uint4 pb = *(const uint4*)(pA + s * 32 + q * 8 + 4);
            bf16x8 Ah2 = { (short)(pa.x >> 16), (short)(pa.y >> 16),
                           (short)(pa.z >> 16), (short)(pa.w >> 16),
                           (short)(pb.x >> 16), (short)(pb.y >> 16),
                           (short)(pb.z >> 16), (short)(pb.w >> 16) };
            bf16x8 Al2 = { (short)pa.x, (short)pa.y, (short)pa.z, (short)pa.w,
                           (short)pb.x, (short)pb.y, (short)pb.z, (short)pb.w };
            bf16x8 Bh = *(const bf16x8*)(pWh + s * 32);
            bf16x8 Bl = *(const bf16x8*)(pWl + s * 32);
            ac = __builtin_amdgcn_mfma_f32_16x16x32_bf16(Ah2, Bh, ac, 0, 0, 0);
            ac = __builtin_amdgcn_mfma_f32_16x16x32_bf16(Ah2, Bl, ac, 0, 0, 0);
            ac = __builtin_amdgcn_mfma_f32_16x16x32_bf16(Al2, Bh, ac, 0, 0, 0);
        }
        const float b2 = B2[ln];
        #pragma unroll
        for (int r = 0; r < 4; ++r)
            embs[(wv * 16 + q * 4 + r) * CD + ln] = ac[r] + b2;
    }
    __syncthreads();                 // embs ready

    // ---- phase D: wave = code quarter (8 tiles); 2 token-sets ----
    {
        bf16x8 Ae[2];                // K-packed: q<2 -> e_hi, q>=2 -> e_lo
        #pragma unroll
        for (int ms = 0; ms < 2; ++ms) {
            const float* ep = embs + (ms * 16 + ln) * CD + (q & 1) * 8;
            float4 ea = *(const float4*)ep;
            float4 eb = *(const float4*)(ep + 4);
            float ev[8] = { ea.x, ea.y, ea.z, ea.w, eb.x, eb.y, eb.z, eb.w };
            #pragma unroll
            for (int j = 0; j < 8; ++j) {
                short hi = f2bf(ev[j]);
                Ae[ms][j] = (q < 2) ? hi : f2bf(ev[j] - bf2f(hi));
            }
        }
        float d1[2][4], d2[2][4]; int i1[2][4], i2[2][4];
        #pragma unroll
        for (int ms = 0; ms < 2; ++ms)
            #pragma unroll
            for (int r = 0; r < 4; ++r) {
                d1[ms][r] = d2[ms][r] = 3.4e38f;
                i1[ms][r] = i2[ms][r] = 0x7fffffff;
            }

        const u16* pC = wsCB + (wv * 8) * 1024 + l * 8;
        #pragma unroll
        for (int tb = 0; tb < 8; ++tb) {
            const u16* pt = pC + tb * 1024;
            bf16x8 Bh = *(const bf16x8*)pt;
            bf16x8 Bl = *(const bf16x8*)(pt + 512);
            const int ci = (wv * 8 + tb) * 16 + ln;
            const float cn = n32[ci];
            #pragma unroll
            for (int ms = 0; ms < 2; ++ms) {
                f32x4 a = (f32x4){0.f, 0.f, 0.f, 0.f};
                a = __builtin_amdgcn_mfma_f32_16x16x32_bf16(Ae[ms], Bh, a, 0, 0, 0);
                a = __builtin_amdgcn_mfma_f32_16x16x32_bf16(Ae[ms], Bl, a, 0, 0, 0);
                #pragma unroll
                for (int r = 0; r < 4; ++r) {
                    float d = fmaf(-2.f, a[r], cn);
                    if (d < d1[ms][r]) {
                        d2[ms][r] = d1[ms][r]; i2[ms][r] = i1[ms][r];
                        d1[ms][r] = d; i1[ms][r] = ci;
                    } else if (d < d2[ms][r]) { d2[ms][r] = d; i2[ms][r] = ci; }
                }
            }
        }
        // reduce over the 16 lanes of the quad (tie -> low index)
        #pragma unroll
        for (int off = 8; off >= 1; off >>= 1) {
            #pragma unroll
            for (int ms = 0; ms < 2; ++ms)
                #pragma unroll
                for (int r = 0; r < 4; ++r) {
                    float od1 = __shfl_down(d1[ms][r], off, 16);
                    int   oi1 = __shfl_down(i1[ms][r], off, 16);
                    float od2 = __shfl_down(d2[ms][r], off, 16);
                    int   oi2 = __shfl_down(i2[ms][r], off, 16);
                    bool ob = (od1 < d1[ms][r]) ||
                              (od1 == d1[ms][r] && oi1 < i1[ms][r]);
                    float n1d, n2d; int n1i, n2i;
                    if (ob) {
                        n1d = od1; n1i = oi1;
                        bool t2 = (d1[ms][r] < od2) ||
                                  (d1[ms][r] == od2 && i1[ms][r] < oi2);
                        n2d = t2 ? d1[ms][r] : od2; n2i = t2 ? i1[ms][r] : oi2;
                    } else {
                        n1d = d1[ms][r]; n1i = i1[ms][r];
                        bool t2 = (od1 < d2[ms][r]) ||
                                  (od1 == d2[ms][r] && oi1 < i2[ms][r]);
                        n2d = t2 ? od1 : d2[ms][r]; n2i = t2 ? oi1 : i2[ms][r];
                    }
                    d1[ms][r] = n1d; i1[ms][r] = n1i;
                    d2[ms][r] = n2d; i2[ms][r] = n2i;
                }
        }
        if (ln == 0) {
            #pragma unroll
            for (int ms = 0; ms < 2; ++ms)
                #pragma unroll
                for (int r = 0; r < 4; ++r) {
                    const int m = ms * 16 + q * 4 + r;
                    redD[wv][m][0] = d1[ms][r]; redD[wv][m][1] = d2[ms][r];
                    redI[wv][m][0] = i1[ms][r]; redI[wv][m][1] = i2[ms][r];
                }
        }
    }
    __syncthreads();

    if (tid < OBS) {                 // merge 4 quarters, flag, write idx
        const int m = tid;
        float d1 = redD[0][m][0], d2 = redD[0][m][1];
        int   i1 = redI[0][m][0], i2 = redI[0][m][1];
        #pragma unroll
        for (int h = 1; h < 4; ++h) {
            #pragma unroll
            for (int e = 0; e < 2; ++e) {
                float db = redD[h][m][e]; int ib = redI[h][m][e];
                if (db < d1 || (db == d1 && ib < i1)) {
                    d2 = d1; i2 = i1; d1 = db; i1 = ib;
                } else if (db < d2 || (db == d2 && ib < i2)) { d2 = db; i2 = ib; }
            }
        }
        const int T = blk * OBS + m;
        idxbuf[T] = i1;
        if (d2 - d1 < EPS) {
            int pos = atomicAdd(fcnt, 1);
            flist[pos] = T;
        }
    }
}

// ---------------------------------------------------------------------------
// Kernel 2: fp64 exact re-solve for flagged tokens (from ORIGINAL fp32 data).
// ---------------------------------------------------------------------------
__global__ void __launch_bounds__(256) fixup_kernel(
    const float* __restrict__ obs,
    const float* __restrict__ W0, const float* __restrict__ B0,
    const float* __restrict__ W1, const float* __restrict__ B1,
    const float* __restrict__ W2, const float* __restrict__ B2,
    const float* __restrict__ cb, const double* __restrict__ n64,
    const int* __restrict__ fcnt, const int* __restrict__ flist,
    int* __restrict__ idxbuf)
{
    __shared__ double h0s[HD];
    __shared__ double h1s[HD];
    __shared__ double ep[16][17];
    __shared__ double es[CD];
    __shared__ double dmin[256];
    __shared__ int    imin[256];

    int n = *fcnt;
    if (n > BATCH * OBS) n = BATCH * OBS;
    const int j = threadIdx.x;

    for (int f = blockIdx.x; f < n; f += gridDim.x) {
        const int T = flist[f];
        const int b = T >> 5, t = T & 31;
        const double x = (double)obs[b * OBS + t];
        {
            double a = fma(x, (double)W0[j], (double)W0[(1 + t) * HD + j])
                     + (double)B0[j];
            h0s[j] = a > 0.0 ? a : 0.0;
        }
        __syncthreads();
        {
            double s = 0.0;
            for (int k = 0; k < HD; ++k)
                s = fma(h0s[k], (double)W1[k * HD + j], s);
            s += (double)B1[j];
            h1s[j] = s > 0.0 ? s : 0.0;
        }
        __syncthreads();
        {
            const int d = j & 15, part = j >> 4;
            double s = 0.0;
            for (int k = part * 16; k < part * 16 + 16; ++k)
                s = fma(h1s[k], (double)W2[k * CD + d], s);
            ep[part][d] = s;
        }
        __syncthreads();
        if (j < CD) {
            double s = 0.0;
            for (int p = 0; p < 16; ++p) s += ep[p][j];
            es[j] = s + (double)B2[j];
        }
        __syncthreads();
        {
            double best = 1e300; int bi = 0x7fffffff;
            for (int c = j; c < NC; c += 256) {
                double dot = 0.0;
                #pragma unroll
                for (int qq = 0; qq < CD; ++qq)
                    dot = fma(es[qq], (double)cb[c * CD + qq], dot);
                double D = n64[c] - 2.0 * dot;
                if (D < best || (D == best && c < bi)) { best = D; bi = c; }
            }
            dmin[j] = best; imin[j] = bi;
        }
        __syncthreads();
        if (j == 0) {
            double best = dmin[0]; int bi = imin[0];
            for (int k = 1; k < 256; ++k)
                if (dmin[k] < best || (dmin[k] == best && imin[k] < bi)) {
                    best = dmin[k]; bi = imin[k];
                }
            idxbuf[T] = bi;
        }
        __syncthreads();
    }
}

// ---------------------------------------------------------------------------
// Kernel 3: decoder MLP 512 -> 256 -> 256 -> 32, 16 batch rows per block.
// ---------------------------------------------------------------------------
__global__ void __launch_bounds__(256) decoder_kernel(
    const int* __restrict__ idx, const float* __restrict__ cbk,
    const float* __restrict__ W0, const float* __restrict__ B0,
    const float* __restrict__ W1, const float* __restrict__ B1,
    const float* __restrict__ W2, const float* __restrict__ B2,
    float* __restrict__ out)
{
    __shared__ float qb[16][512];
    __shared__ float hb[16][256];
    const int tid = threadIdx.x;
    const int row0 = blockIdx.x * 16;

    {
        const int base = row0 * OBS;
        #pragma unroll
        for (int m = 0; m < 2; ++m) {
            int g = tid * 2 + m;
            int ciq = idx[base + g];
            const float4* src = (const float4*)(cbk + ciq * CD);
            float4* dst = (float4*)&qb[g >> 5][(g & 31) * CD];
            dst[0] = src[0]; dst[1] = src[1]; dst[2] = src[2]; dst[3] = src[3];
        }
    }
    __syncthreads();

    const int jg = tid & 63, tg = tid >> 6;
    const int j0 = jg * 4, r0 = tg * 4;

    {
        float acA[4][4], acB[4][4];
        #pragma unroll
        for (int tt = 0; tt < 4; ++tt)
            #pragma unroll
            for (int u = 0; u < 4; ++u) { acA[tt][u] = 0.f; acB[tt][u] = 0.f; }
        for (int k = 0; k < 512; k += 4) {
            float hr[4][4];
            #pragma unroll
            for (int tt = 0; tt < 4; ++tt) {
                float4 hv = *(const float4*)&qb[r0 + tt][k];
                hr[tt][0] = hv.x; hr[tt][1] = hv.y; hr[tt][2] = hv.z; hr[tt][3] = hv.w;
            }
            #pragma unroll
            for (int p = 0; p < 4; ++p) {
                float4 w = *(const float4*)(W0 + (k + p) * 256 + j0);
                if (p < 2) {
                    #pragma unroll
                    for (int tt = 0; tt < 4; ++tt) {
                        acA[tt][0] = fmaf(hr[tt][p], w.x, acA[tt][0]);
                        acA[tt][1] = fmaf(hr[tt][p], w.y, acA[tt][1]);
                        acA[tt][2] = fmaf(hr[tt][p], w.z, acA[tt][2]);
                        acA[tt][3] = fmaf(hr[tt][p], w.w, acA[tt][3]);
                    }
                } else {
                    #pragma unroll
                    for (int tt = 0; tt < 4; ++tt) {
                        acB[tt][0] = fmaf(hr[tt][p], w.x, acB[tt][0]);
                        acB[tt][1] = fmaf(hr[tt][p], w.y, acB[tt][1]);
                        acB[tt][2] = fmaf(hr[tt][p], w.z, acB[tt][2]);
                        acB[tt][3] = fmaf(hr[tt][p], w.w, acB[tt][3]);
                    }
                }
            }
        }
        #pragma unroll
        for (int tt = 0; tt < 4; ++tt)
            #pragma unroll
            for (int u = 0; u < 4; ++u)
                hb[r0 + tt][j0 + u] = fmaxf((acA[tt][u] + acB[tt][u]) + B0[j0 + u], 0.f);
    }
    __syncthreads();

    float* h2 = &qb[0][0];
    {
        float acA[4][4], acB[4][4];
        #pragma unroll
        for (int tt = 0; tt < 4; ++tt)
            #pragma unroll
            for (int u = 0; u < 4; ++u) { acA[tt][u] = 0.f; acB[tt][u] = 0.f; }
        for (int k = 0; k < 256; k += 4) {
            float hr[4][4];
            #pragma unroll
            for (int tt = 0; tt < 4; ++tt) {
                float4 hv = *(const float4*)&hb[r0 + tt][k];
                hr[tt][0] = hv.x; hr[tt][1] = hv.y; hr[tt][2] = hv.z; hr[tt][3] = hv.w;
            }
            #pragma unroll
            for (int p = 0; p < 4; ++p) {
                float4 w = *(const float4*)(W1 + (k + p) * 256 + j0);
                if (p < 2) {
                    #pragma unroll
                    for (int tt = 0; tt < 4; ++tt) {
                        acA[tt][0] = fmaf(hr[tt][p], w.x, acA[tt][0]);
                        acA[tt][1] = fmaf(hr[tt][p], w.y, acA[tt][1]);
                        acA[tt][2] = fmaf(hr[tt][p], w.z, acA[tt][2]);
                        acA[tt][3] = fmaf(hr[tt][p], w.w, acA[tt][3]);
                    }
                } else {
                    #pragma unroll
                    for (int tt = 0; tt < 4; ++tt) {
                        acB[tt][0] = fmaf(hr[tt][p], w.x, acB[tt][0]);
                        acB[tt][1] = fmaf(hr[tt][p], w.y, acB[tt][1]);
                        acB[tt][2] = fmaf(hr[tt][p], w.z, acB[tt][2]);
                        acB[tt][3] = fmaf(hr[tt][p], w.w, acB[tt][3]);
                    }
                }
            }
        }
        __syncthreads();
        #pragma unroll
        for (int tt = 0; tt < 4; ++tt)
            #pragma unroll
            for (int u = 0; u < 4; ++u)
                h2[(r0 + tt) * 256 + j0 + u] =
                    fmaxf((acA[tt][u] + acB[tt][u]) + B1[j0 + u], 0.f);
    }
    __syncthreads();

    {
        const int c  = tid & 31;
        const int rg = tid >> 5;
        for (int rr = rg; rr < 16; rr += 8) {
            float a0 = 0.f, a1 = 0.f, a2 = 0.f, a3 = 0.f;
            #pragma unroll 4
            for (int k = 0; k < 256; k += 4) {
                float4 hv = *(const float4*)&h2[rr * 256 + k];
                a0 = fmaf(hv.x, W2[(k + 0) * 32 + c], a0);
                a1 = fmaf(hv.y, W2[(k + 1) * 32 + c], a1);
                a2 = fmaf(hv.z, W2[(k + 2) * 32 + c], a2);
                a3 = fmaf(hv.w, W2[(k + 3) * 32 + c], a3);
            }
            out[(row0 + rr) * 32 + c] = ((a0 + a1) + (a2 + a3)) + B2[c];
        }
    }
}

// ---------------------------------------------------------------------------
extern "C" void kernel_launch(void* const* d_in, const int* in_sizes, int n_in,
                              void* d_out, int out_size, void* d_ws, size_t ws_size,
                              hipStream_t stream) {
    (void)in_sizes; (void)n_in; (void)out_size; (void)ws_size;
    const float* obs = (const float*)d_in[0];
    const float* eW0 = (const float*)d_in[1];
    const float* eb0 = (const float*)d_in[2];
    const float* eW1 = (const float*)d_in[3];
    const float* eb1 = (const float*)d_in[4];
    const float* eW2 = (const float*)d_in[5];
    const float* eb2 = (const float*)d_in[6];
    const float* dW0 = (const float*)d_in[7];
    const float* db0 = (const float*)d_in[8];
    const float* dW1 = (const float*)d_in[9];
    const float* db1 = (const float*)d_in[10];
    const float* dW2 = (const float*)d_in[11];
    const float* db2 = (const float*)d_in[12];
    const float* cb  = (const float*)d_in[13];

    char*   ws    = (char*)d_ws;
    float*  n32   = (float*)ws;                          // 2 KB
    double* n64   = (double*)(ws + 4096);                // 4 KB
    int*    fcnt  = (int*)(ws + 8192);                   // 4 B
    int*    flist = (int*)(ws + 8448);                   // 1 MB
    int*    idxb  = (int*)(ws + 8448 + 1048576);         // 1 MB
    u16*    wsW1  = (u16*)(ws + 4194304);                // 256 KB
    u16*    wsW2  = (u16*)(ws + 4194304 + 262144);       // 16.5 KB (pad 32 KB)
    u16*    wsCB  = (u16*)(ws + 4194304 + 262144 + 32768); // 64 KB

    prep_kernel<<<259, 256, 0, stream>>>(cb, eW1, eW2, n32, n64, fcnt,
                                         wsW1, wsW2, wsCB);
    encoder_kernel<<<BATCH, 256, 0, stream>>>(obs, eW0, eb0, eb1, eb2,
                                              wsW1, wsW2, wsCB, n32,
                                              idxb, fcnt, flist);
    fixup_kernel<<<256, 256, 0, stream>>>(obs, eW0, eb0, eW1, eb1, eW2, eb2,
                                          cb, n64, fcnt, flist, idxb);
    decoder_kernel<<<BATCH / 16, 256, 0, stream>>>(idxb, cb, dW0, db0, dW1, db1,
                                                   dW2, db2, (float*)d_out);
}